// Round 13
// baseline (130.658 us; speedup 1.0000x reference)
//
#include <hip/hip_runtime.h>
#include <hip/hip_bf16.h>

// LogicConv3d: B=64, C=32, H=32, W=32, K=64, P=784, S=16 gathers/side.
// R13: all-L2 gathers at 2x occupancy.
//  - R12 post-mortem: ds pipe NOT the binder (2x ds insts cost only +3.4us).
//    Corrected pipe model (/4 SIMDs): all pipes ~5-6us vs main ~22us ->
//    latency-bound at 4 waves/SIMD, capped by the 128KB LDS staging.
//  - R13 drops LDS entirely: both images gathered from L2 (x=8MB; per-XCD
//    footprint ~1MB with bp-fastest grid; lane=p keeps 8 lanes/64B-line
//    coalescing). 256-thr blocks + __launch_bounds__(256,8) -> VGPR<=64 ->
//    8 waves/SIMD (m69: occupancy halves at VGPR>64).
//  - Tree restructured leaf-pair-wise (load 2 leaves -> layer0+layer1
//    accumulate) to fit 64 VGPR: y1[8] f2 x 2 imgs = 32 + 16 load regs.
//  - float2 ext_vector aligned(4) loads -> global_load_dwordx2 (gfx950
//    unaligned-access-mode) -> VMEM inst count halves.

#define B_  64
#define C_  32
#define H_  32
#define W_  32
#define K_  64
#define P_  784
#define CHW (C_*H_*W_)      // 32768 floats = 128 KB
#define HW  (H_*W_)         // 1024
#define SITES (K_*P_)       // 50176
#define NPAIR (P_/2)        // 392

__constant__ float COEF_[16][4] = {
    {0, 0, 0, 0}, {0, 0, 0, 1}, {0, 1, 0, -1}, {0, 1, 0, 0},
    {0, 0, 1, -1}, {0, 0, 1, 0}, {0, 1, 1, -2}, {0, 1, 1, -1},
    {1, -1, -1, 1}, {1, -1, -1, 2}, {1, 0, -1, 0}, {1, 0, -1, 1},
    {1, -1, 0, 0}, {1, -1, 0, 1}, {1, 0, 0, -1}, {1, 0, 0, 0}
};

typedef float f2 __attribute__((ext_vector_type(2)));
typedef float f2u __attribute__((ext_vector_type(2), aligned(4)));

// ---- kernel 1: tiny prep = bases (0..2047) + coefs (2048..4031) ----
__global__ __launch_bounds__(256) void prep_kernel(
    const int* __restrict__ a_idx, const int* __restrict__ b_idx,
    const float* __restrict__ w0, const float* __restrict__ w1,
    const float* __restrict__ w2, const float* __restrict__ w3,
    const float* __restrict__ w4,
    int* __restrict__ baseAB,        // [K_][32] byte offsets
    float4* __restrict__ cws)        // [K_*31]
{
    const int t = blockIdx.x * 256 + threadIdx.x;
    if (t < K_ * 32) {
        const int k = t >> 5;
        const int j = t & 31;
        const int* src = (j < 16) ? a_idx : b_idx;
        const int l = j & 15;
        const size_t ii = ((size_t)k * P_ * 16 + l) * 3;   // site (k, p=0, l)
        const int h = src[ii + 0];
        const int w = src[ii + 1];
        const int c = src[ii + 2];
        baseAB[t] = (c << 12) + (h << 7) + (w << 2);       // bytes
    } else if (t < K_ * 32 + K_ * 31) {
        const int tt = t - K_ * 32;
        const int k = tt / 31;
        const int node = tt - k * 31;
        int d, l;
        if      (node < 16) { d = 0; l = node; }
        else if (node < 24) { d = 1; l = node - 16; }
        else if (node < 28) { d = 2; l = node - 24; }
        else if (node < 30) { d = 3; l = node - 28; }
        else                { d = 4; l = 0; }
        const float* W;
        switch (d) {
            case 0: W = w0; break;
            case 1: W = w1; break;
            case 2: W = w2; break;
            case 3: W = w3; break;
            default: W = w4; break;
        }
        const float* row = W + ((size_t)l * K_ + k) * 16;
        float m = row[0];
        #pragma unroll
        for (int o = 1; o < 16; ++o) m = fmaxf(m, row[o]);
        float e[16];
        float Z = 0.0f;
        #pragma unroll
        for (int o = 0; o < 16; ++o) { e[o] = expf(row[o] - m); Z += e[o]; }
        const float inv = 1.0f / Z;
        float c0 = 0.f, c1 = 0.f, c2 = 0.f, c3 = 0.f;
        #pragma unroll
        for (int o = 0; o < 16; ++o) {
            c0 += e[o] * COEF_[o][0];
            c1 += e[o] * COEF_[o][1];
            c2 += e[o] * COEF_[o][2];
            c3 += e[o] * COEF_[o][3];
        }
        cws[tt] = make_float4(c0 * inv, c1 * inv, c2 * inv, c3 * inv);
    }
}

__device__ __forceinline__ f2 ld2(const char* p) {
    return *(const f2u*)p;     // global_load_dwordx2, 4B-aligned ok on gfx950
}

// y = c0 + c1*a + c2*b + c3*a*b == fma(b, fma(c3,a,c2), fma(c1,a,c0))
__device__ __forceinline__ f2 binop2(f2 a, f2 b, float4 c) {
    f2 r;
    r.x = fmaf(b.x, fmaf(c.w, a.x, c.z), fmaf(c.y, a.x, c.x));
    r.y = fmaf(b.y, fmaf(c.w, a.y, c.z), fmaf(c.y, a.y, c.x));
    return r;
}

// ---- kernel 2: main. bid = kt*32 + bp (bp fastest -> XCD shares bp%8).
//      256 thr = 2 groups of 128; group owns one k; thread = p-pair x 2 imgs.
__global__ __launch_bounds__(256, 8) void logicconv_main(
    const float* __restrict__ x,
    const int* __restrict__ baseAB,
    const float4* __restrict__ cws,
    float* __restrict__ out)
{
    const int tid = threadIdx.x;
    const int kt  = blockIdx.x >> 5;   // 0..31 (slow): k-pair
    const int bp  = blockIdx.x & 31;   // 0..31 (fast): image pair
    const int b0  = bp * 2;

    const int g    = __builtin_amdgcn_readfirstlane(tid >> 7);   // 0..1
    const int lane = tid & 127;
    const int k    = kt * 2 + g;

    const int*    __restrict__ bA = baseAB + k * 32;          // s_load
    const float4* __restrict__ cw = cws + (size_t)k * 31;     // s_load
    const char* x0 = (const char*)(x + (size_t)b0 * CHW);       // even image
    const char* x1 = x0 + (size_t)CHW * 4;                      // odd image
    float* __restrict__ o0 = out + ((size_t)b0 * K_ + k) * P_;
    float* __restrict__ o1 = o0 + (size_t)K_ * P_;

    for (int s = 0; s < 4; ++s) {
        const int t = s * 128 + lane;          // pair index
        if (t < NPAIR) {
            const unsigned row  = (unsigned)t / 14u;             // (2t)/28
            const unsigned disp = 8u * (unsigned)t + 16u * row;  // bytes

            f2 y1e[8], y1o[8];
            #pragma unroll
            for (int m = 0; m < 8; ++m) {      // leaf-pair (2m, 2m+1)
                const unsigned eaL = (unsigned)bA[2*m]        + disp;
                const unsigned eaR = (unsigned)bA[2*m + 1]    + disp;
                const unsigned ebL = (unsigned)bA[16 + 2*m]   + disp;
                const unsigned ebR = (unsigned)bA[16 + 2*m+1] + disp;
                const f2 aE0 = ld2(x0 + eaL), bE0 = ld2(x0 + ebL);
                const f2 aE1 = ld2(x0 + eaR), bE1 = ld2(x0 + ebR);
                const f2 aO0 = ld2(x1 + eaL), bO0 = ld2(x1 + ebL);
                const f2 aO1 = ld2(x1 + eaR), bO1 = ld2(x1 + ebR);
                const f2 e0 = binop2(aE0, bE0, cw[2*m]);
                const f2 e1 = binop2(aE1, bE1, cw[2*m + 1]);
                const f2 q0 = binop2(aO0, bO0, cw[2*m]);
                const f2 q1 = binop2(aO1, bO1, cw[2*m + 1]);
                y1e[m] = binop2(e0, e1, cw[16 + m]);   // layer-1 fused
                y1o[m] = binop2(q0, q1, cw[16 + m]);
            }
            #pragma unroll
            for (int l = 0; l < 4; ++l) {      // layer 2
                y1e[l] = binop2(y1e[2*l], y1e[2*l+1], cw[24 + l]);
                y1o[l] = binop2(y1o[2*l], y1o[2*l+1], cw[24 + l]);
            }
            #pragma unroll
            for (int l = 0; l < 2; ++l) {      // layer 3
                y1e[l] = binop2(y1e[2*l], y1e[2*l+1], cw[28 + l]);
                y1o[l] = binop2(y1o[2*l], y1o[2*l+1], cw[28 + l]);
            }
            const f2 re = binop2(y1e[0], y1e[1], cw[30]);   // layer 4
            const f2 ro = binop2(y1o[0], y1o[1], cw[30]);
            *(f2u*)(o0 + 2 * t) = re;
            *(f2u*)(o1 + 2 * t) = ro;
        }
    }
}

extern "C" void kernel_launch(void* const* d_in, const int* in_sizes, int n_in,
                              void* d_out, int out_size, void* d_ws, size_t ws_size,
                              hipStream_t stream) {
    const float* x     = (const float*)d_in[0];
    const float* w0    = (const float*)d_in[1];
    const float* w1    = (const float*)d_in[2];
    const float* w2    = (const float*)d_in[3];
    const float* w3    = (const float*)d_in[4];
    const float* w4    = (const float*)d_in[5];
    const int*   a_idx = (const int*)d_in[6];
    const int*   b_idx = (const int*)d_in[7];
    float* out = (float*)d_out;

    // ws layout: baseAB (8 KB) | cws (32 KB)
    int*    baseAB = (int*)d_ws;
    float4* cws    = (float4*)((char*)d_ws + (size_t)K_ * 32 * 4);

    prep_kernel<<<16, 256, 0, stream>>>(a_idx, b_idx, w0, w1, w2, w3, w4,
                                        baseAB, cws);

    logicconv_main<<<32 * 32, 256, 0, stream>>>(x, baseAB, cws, out);
}

// Round 14
// 30.020 us; speedup vs baseline: 4.3523x; 4.3523x over previous
//
#include <hip/hip_runtime.h>
#include <hip/hip_bf16.h>

// LogicConv3d: B=64, C=32, H=32, W=32, K=64, P=784, S=16 gathers/side.
// R14: SINGLE fused kernel. R10's dual-pipe main (best: 30.2us) had ~7us of
// pure structure: prep-kernel exec + graph dependency boundary. Each block
// only needs its own 8 k's worth of bases (256 ints) + coefs (248 float4),
// cheap to compute redundantly in the prologue (overlaps staging loads):
//  - stage even image 128KB -> LDS (all 1024 threads, float4)
//  - threads 0..255: pack 8k x 32 base offsets -> LDS
//  - threads 256..503: softmax(w).COEF for 8k x 31 nodes -> LDS
//  - one barrier; then R10's exact main loop (LDS even-gather via ds_read2,
//    global odd-gather, batched issue, analytic disp, float2 stores).
// Coefs now come from LDS (uniform-addr ds_read_b128 broadcast) instead of
// s_load; bases from LDS hoisted once. R13 lesson kept: no forced occupancy,
// launch_bounds(1024,4) = VGPR cap 128, no spills.

#define B_  64
#define C_  32
#define H_  32
#define W_  32
#define K_  64
#define P_  784
#define CHW (C_*H_*W_)      // 32768 floats = 128 KB
#define HW  (H_*W_)         // 1024
#define SITES (K_*P_)       // 50176
#define NPAIR (P_/2)        // 392

__constant__ float COEF_[16][4] = {
    {0, 0, 0, 0}, {0, 0, 0, 1}, {0, 1, 0, -1}, {0, 1, 0, 0},
    {0, 0, 1, -1}, {0, 0, 1, 0}, {0, 1, 1, -2}, {0, 1, 1, -1},
    {1, -1, -1, 1}, {1, -1, -1, 2}, {1, 0, -1, 0}, {1, 0, -1, 1},
    {1, -1, 0, 0}, {1, -1, 0, 1}, {1, 0, 0, -1}, {1, 0, 0, 0}
};

// y = c0 + c1*a + c2*b + c3*a*b == fma(b, fma(c3,a,c2), fma(c1,a,c0))
__device__ __forceinline__ float binop(float a, float b, float4 c) {
    return fmaf(b, fmaf(c.w, a, c.z), fmaf(c.y, a, c.x));
}

// ---- the ONE kernel. bid = kg*32 + bp. 1024 thr, 1 block/CU. ----
__global__ __launch_bounds__(1024, 4) void logicconv_fused(
    const float* __restrict__ x,
    const int* __restrict__ a_idx, const int* __restrict__ b_idx,
    const float* __restrict__ w0, const float* __restrict__ w1,
    const float* __restrict__ w2, const float* __restrict__ w3,
    const float* __restrict__ w4,
    float* __restrict__ out)
{
    __shared__ float  simg[CHW];      // 128 KB even image
    __shared__ int    sBase[256];     // [kloc][j]: j<16 A-side, j>=16 B-side
    __shared__ float4 sCoef[248];     // [kloc][node 0..30]

    const int tid = threadIdx.x;
    const int kg  = blockIdx.x >> 5;   // 0..7  (slow)
    const int bp  = blockIdx.x & 31;   // 0..31 (fast)
    const int b0  = bp * 2;

    // ---- prologue A: stage EVEN image (all threads, coalesced float4) ----
    {
        const float4* xi = (const float4*)(x + (size_t)b0 * CHW);
        float4* si = (float4*)simg;
        #pragma unroll
        for (int j = 0; j < 8; ++j)
            si[tid + j * 1024] = xi[tid + j * 1024];
    }

    // ---- prologue B: bases for this block's 8 k's ----
    if (tid < 256) {
        const int kloc = tid >> 5;
        const int j    = tid & 31;
        const int k    = kg * 8 + kloc;
        const int* src = (j < 16) ? a_idx : b_idx;
        const int l    = j & 15;
        const size_t ii = ((size_t)k * P_ * 16 + l) * 3;   // (k, p=0, l)
        sBase[tid] = (src[ii + 2] << 12) + (src[ii + 0] << 7) + (src[ii + 1] << 2);
    }
    // ---- prologue C: coefs for this block's 8 k's (248 jobs) ----
    else if (tid < 504) {
        const int job  = tid - 256;         // 0..247
        const int kloc = job / 31;
        const int node = job - kloc * 31;
        const int k    = kg * 8 + kloc;
        int d, l;
        if      (node < 16) { d = 0; l = node; }
        else if (node < 24) { d = 1; l = node - 16; }
        else if (node < 28) { d = 2; l = node - 24; }
        else if (node < 30) { d = 3; l = node - 28; }
        else                { d = 4; l = 0; }
        const float* W;
        switch (d) {
            case 0: W = w0; break;
            case 1: W = w1; break;
            case 2: W = w2; break;
            case 3: W = w3; break;
            default: W = w4; break;
        }
        const float* row = W + ((size_t)l * K_ + k) * 16;
        float m = row[0];
        #pragma unroll
        for (int o = 1; o < 16; ++o) m = fmaxf(m, row[o]);
        float e[16];
        float Z = 0.0f;
        #pragma unroll
        for (int o = 0; o < 16; ++o) { e[o] = expf(row[o] - m); Z += e[o]; }
        const float inv = 1.0f / Z;
        float c0 = 0.f, c1 = 0.f, c2 = 0.f, c3 = 0.f;
        #pragma unroll
        for (int o = 0; o < 16; ++o) {
            c0 += e[o] * COEF_[o][0];
            c1 += e[o] * COEF_[o][1];
            c2 += e[o] * COEF_[o][2];
            c3 += e[o] * COEF_[o][3];
        }
        sCoef[job] = make_float4(c0 * inv, c1 * inv, c2 * inv, c3 * inv);
    }
    __syncthreads();

    // ---- main: 8 groups of 128 threads; group owns one k ----
    const int g    = __builtin_amdgcn_readfirstlane(tid >> 7);
    const int lane = tid & 127;
    const int k    = kg * 8 + g;

    const int*    __restrict__ bA = sBase + g * 32;     // LDS, loop-invariant
    const float4* __restrict__ cw = sCoef + g * 31;     // LDS, uniform addr
    const char*   sb = (const char*)simg;
    const char*   x1 = (const char*)(x + (size_t)(b0 + 1) * CHW);  // odd image
    float* __restrict__ o0 = out + ((size_t)b0 * K_ + k) * P_;
    float* __restrict__ o1 = o0 + (size_t)K_ * P_;

    for (int s = 0; s < 4; ++s) {
        const int t = s * 128 + lane;          // pair index
        if (t < NPAIR) {
            const unsigned row  = (unsigned)t / 14u;             // (2t)/28
            const unsigned disp = 8u * (unsigned)t + 16u * row;  // bytes

            float2 ye[16], yo[16];
            #pragma unroll
            for (int h = 0; h < 2; ++h) {
                unsigned ea[8], eb[8];
                #pragma unroll
                for (int j = 0; j < 8; ++j) {
                    ea[j] = (unsigned)bA[h*8 + j]      + disp;
                    eb[j] = (unsigned)bA[16 + h*8 + j] + disp;
                }
                // 1) issue ALL odd-image global loads for this half
                float od[32];
                #pragma unroll
                for (int j = 0; j < 8; ++j) {
                    od[4*j+0] = *(const float*)(x1 + ea[j]);
                    od[4*j+1] = *(const float*)(x1 + ea[j] + 4);
                    od[4*j+2] = *(const float*)(x1 + eb[j]);
                    od[4*j+3] = *(const float*)(x1 + eb[j] + 4);
                }
                // 2) issue ALL even-image LDS pair reads (ds_read2_b32)
                float ev[32];
                #pragma unroll
                for (int j = 0; j < 8; ++j) {
                    ev[4*j+0] = *(const float*)(sb + ea[j]);
                    ev[4*j+1] = *(const float*)(sb + ea[j] + 4);
                    ev[4*j+2] = *(const float*)(sb + eb[j]);
                    ev[4*j+3] = *(const float*)(sb + eb[j] + 4);
                }
                // 3) layer-0 for this half
                #pragma unroll
                for (int j = 0; j < 8; ++j) {
                    const int l = h*8 + j;
                    const float4 c = cw[l];
                    ye[l].x = binop(ev[4*j+0], ev[4*j+2], c);
                    ye[l].y = binop(ev[4*j+1], ev[4*j+3], c);
                    yo[l].x = binop(od[4*j+0], od[4*j+2], c);
                    yo[l].y = binop(od[4*j+1], od[4*j+3], c);
                }
            }
            #pragma unroll
            for (int l = 0; l < 8; ++l) {
                const float4 c = cw[16 + l];
                ye[l].x = binop(ye[2*l].x, ye[2*l+1].x, c);
                ye[l].y = binop(ye[2*l].y, ye[2*l+1].y, c);
                yo[l].x = binop(yo[2*l].x, yo[2*l+1].x, c);
                yo[l].y = binop(yo[2*l].y, yo[2*l+1].y, c);
            }
            #pragma unroll
            for (int l = 0; l < 4; ++l) {
                const float4 c = cw[24 + l];
                ye[l].x = binop(ye[2*l].x, ye[2*l+1].x, c);
                ye[l].y = binop(ye[2*l].y, ye[2*l+1].y, c);
                yo[l].x = binop(yo[2*l].x, yo[2*l+1].x, c);
                yo[l].y = binop(yo[2*l].y, yo[2*l+1].y, c);
            }
            #pragma unroll
            for (int l = 0; l < 2; ++l) {
                const float4 c = cw[28 + l];
                ye[l].x = binop(ye[2*l].x, ye[2*l+1].x, c);
                ye[l].y = binop(ye[2*l].y, ye[2*l+1].y, c);
                yo[l].x = binop(yo[2*l].x, yo[2*l+1].x, c);
                yo[l].y = binop(yo[2*l].y, yo[2*l+1].y, c);
            }
            {
                const float4 c = cw[30];
                float2 re, ro;
                re.x = binop(ye[0].x, ye[1].x, c);
                re.y = binop(ye[0].y, ye[1].y, c);
                ro.x = binop(yo[0].x, yo[1].x, c);
                ro.y = binop(yo[0].y, yo[1].y, c);
                *(float2*)(o0 + 2 * t) = re;   // byte 8t -> 8-aligned
                *(float2*)(o1 + 2 * t) = ro;
            }
        }
    }
}

extern "C" void kernel_launch(void* const* d_in, const int* in_sizes, int n_in,
                              void* d_out, int out_size, void* d_ws, size_t ws_size,
                              hipStream_t stream) {
    const float* x     = (const float*)d_in[0];
    const float* w0    = (const float*)d_in[1];
    const float* w1    = (const float*)d_in[2];
    const float* w2    = (const float*)d_in[3];
    const float* w3    = (const float*)d_in[4];
    const float* w4    = (const float*)d_in[5];
    const int*   a_idx = (const int*)d_in[6];
    const int*   b_idx = (const int*)d_in[7];
    float* out = (float*)d_out;

    logicconv_fused<<<256, 1024, 0, stream>>>(x, a_idx, b_idx,
                                              w0, w1, w2, w3, w4, out);
}